// Round 15
// baseline (411.355 us; speedup 1.0000x reference)
//
#include <hip/hip_runtime.h>

#define NN    16384
#define HD    128
#define G4    512
#define KST   16
#define NRELS 3
#define NPB   32   // nodes per lstm block (2 row-tiles of 16)
#define LOG2E 1.44269504f
#define TT    2.8853901f   // 2*log2(e)

using f16x8 = __attribute__((ext_vector_type(8))) _Float16;
using f32x4 = __attribute__((ext_vector_type(4))) float;

static __device__ __forceinline__ f32x4 f4splat(float v) {
    f32x4 r; r[0] = v; r[1] = v; r[2] = v; r[3] = v; return r;
}
static __device__ __forceinline__ f16x8 load8h(const float* p) {
    const float4 a = ((const float4*)p)[0];
    const float4 b = ((const float4*)p)[1];
    f16x8 r;
    r[0] = (_Float16)a.x; r[1] = (_Float16)a.y; r[2] = (_Float16)a.z; r[3] = (_Float16)a.w;
    r[4] = (_Float16)b.x; r[5] = (_Float16)b.y; r[6] = (_Float16)b.z; r[7] = (_Float16)b.w;
    return r;
}
static __device__ __forceinline__ f32x4 mfma16h(f16x8 a, f16x8 b, f32x4 c) {
    return __builtin_amdgcn_mfma_f32_16x16x32_f16(a, b, c, 0, 0, 0);
}
static __device__ __forceinline__ unsigned short f2h_bits(float f) {
    return __builtin_bit_cast(unsigned short, (_Float16)f);
}
static __device__ __forceinline__ float h2f(unsigned short b) {
    return (float)__builtin_bit_cast(_Float16, b);
}
static __device__ __forceinline__ void barrier_lgkm() {
    asm volatile("s_waitcnt lgkmcnt(0)" ::: "memory");
    __builtin_amdgcn_s_barrier();
}

// ---------------------------------------------------------------------------
// Whh f32 [3][512][128] -> fp16 pre-scaled [3][512][128] (i,f,o x log2e;
// g-quad x 2*log2e) so the lstm can stream 16B frags with zero conversion.
// ---------------------------------------------------------------------------
__global__ __launch_bounds__(256) void whh_cvt(
    const float* __restrict__ Whh, unsigned short* __restrict__ WhhH)
{
    const size_t i = (size_t)blockIdx.x * 256 + threadIdx.x;   // < 3*512*128
    const int row = ((int)(i >> 7)) & 511;
    const float s = ((row >> 7) == 2) ? 2.0f * LOG2E : LOG2E;
    WhhH[i] = f2h_bits(Whh[i] * s);
}

// ---------------------------------------------------------------------------
// C[row,col] = A[row,:] @ W[r][col,:]^T (+bias[r][col]); fp16 inputs, f32 acc.
// MODE 0: f32 out [row*OUTC+col]            (tc = conn @ trans.T)
// MODE 1: fp16 out, gate-quad packed, pre-scaled (i,f,o x log2e; g x 2log2e)
//         quad offset = (r*NN+row)*512 + (col&127)*4 + (col>>7)
// ---------------------------------------------------------------------------
template <int OUTC, int MODE>
__global__ __launch_bounds__(512, 2) void gemm_rt(
    const float* __restrict__ A, const float* __restrict__ W,
    const float* __restrict__ bias, void* __restrict__ outp)
{
    constexpr int CW = OUTC / 8;
    constexpr int CT = CW / 16;
    const int tid = threadIdx.x;
    const int w = tid >> 6, lane = tid & 63;
    const int g = lane >> 4, m = lane & 15;
    const int n0 = blockIdx.x * 64;
    const int r = blockIdx.y;
    const float* Wr = W + (size_t)r * OUTC * HD;

    f32x4 acc[4][CT];
#pragma unroll
    for (int rt = 0; rt < 4; ++rt)
#pragma unroll
        for (int ct = 0; ct < CT; ++ct) acc[rt][ct] = f4splat(0.0f);

#pragma unroll
    for (int kc = 0; kc < 4; ++kc) {
        f16x8 a[4];
#pragma unroll
        for (int rt = 0; rt < 4; ++rt)
            a[rt] = load8h(A + (size_t)(n0 + rt * 16 + m) * HD + kc * 32 + 8 * g);
        f16x8 b[CT];
#pragma unroll
        for (int ct = 0; ct < CT; ++ct)
            b[ct] = load8h(Wr + (size_t)(w * CW + ct * 16 + m) * HD + kc * 32 + 8 * g);
#pragma unroll
        for (int rt = 0; rt < 4; ++rt)
#pragma unroll
            for (int ct = 0; ct < CT; ++ct)
                acc[rt][ct] = mfma16h(a[rt], b[ct], acc[rt][ct]);
    }

#pragma unroll
    for (int rt = 0; rt < 4; ++rt)
#pragma unroll
        for (int ct = 0; ct < CT; ++ct) {
            const int col = w * CW + ct * 16 + m;
            const float bv = bias ? bias[r * OUTC + col] : 0.0f;
#pragma unroll
            for (int e = 0; e < 4; ++e) {
                const int row = n0 + rt * 16 + 4 * g + e;
                const float v = acc[rt][ct][e] + bv;
                if constexpr (MODE == 0) {
                    ((float*)outp)[(size_t)row * OUTC + col] = v;
                } else {
                    const int q = col >> 7;
                    const float s = (q == 2) ? 2.0f * LOG2E : LOG2E;
                    ((unsigned short*)outp)[((size_t)r * NN + row) * G4 + (size_t)(col & 127) * 4 + q] =
                        f2h_bits(v * s);
                }
            }
        }
}

// ---------------------------------------------------------------------------
// NPB=32 with STREAMED Whh: 2x work/wave at 4 waves/SIMD without the resident
// 64-reg Whh (R10's spill fixed). Wave w owns hidden cols w*16+m of all 4
// gate quads for BOTH 16-node row-tiles; per kc it streams 4 B-frags (16B
// ds-free dwordx4 loads) from the pre-converted fp16 Whh in ws — same 16KB
// every step, L2-hot (384KB/XCD). kc0 issued post-cell (hides under barrier).
// Direct 8B gather prefetched 1 step ahead; h dbuf XOR-swizzled; 1 lgkm-only
// barrier/step; rcp-fused exp2 cell (5 exp2 + 2 rcp / element).
// ---------------------------------------------------------------------------
__global__ __launch_bounds__(512, 4) void lstm_kernel(
    const float* __restrict__ x, const int* __restrict__ nbr,
    const unsigned short* __restrict__ WhhH, const float* __restrict__ fcs,
    const float* __restrict__ fcn, const float* __restrict__ bias,
    const unsigned short* __restrict__ xW, float* __restrict__ Xout)
{
    __shared__ unsigned short h_lds[2][NPB * HD];   // fp16, swizzled, dbuf 16KB
    __shared__ int idx_lds[KST * NPB];              // [t][n], idx<<10, 2KB

    const int tid = threadIdx.x;
    const int w = tid >> 6, lane = tid & 63;
    const int g = lane >> 4, m = lane & 15;
    const int n0 = blockIdx.x * NPB;
    const int r = blockIdx.y;
    const unsigned laneoff = (unsigned)(w * 16 + m) * 8u;
    const char* xwr = (const char*)(xW + (size_t)r * NN * G4);
    // per-lane Whh frag base; frag(q,kc) at + q*32768 + kc*64 bytes
    const char* whb = (const char*)WhhH + (size_t)r * G4 * HD * 2
                    + (size_t)(w * 16 + m) * 256 + (size_t)g * 16;

    // anti-phase-lock stagger for co-resident pair
    if ((blockIdx.x >> 8) & 1) {
        asm volatile("s_sleep 32");
        asm volatile("s_sleep 22");
    }

    {   // idx table [t][n], pre-shifted to byte offsets (1024B per node row)
        const int t = tid >> 5, n = tid & 31;
        idx_lds[tid] = nbr[((size_t)r * NN + n0 + n) * KST + t] << 10;
    }

    // step-invariant LDS offsets (ushort units); rt adds +2048 imm
    int rd_off[4], wr_off[4];
#pragma unroll
    for (int kc = 0; kc < 4; ++kc)
        rd_off[kc] = m * HD + ((kc * 32 + 8 * g) ^ ((m & 7) << 3));
#pragma unroll
    for (int e = 0; e < 4; ++e) {
        const int row = 4 * g + e;
        wr_off[e] = row * HD + ((w * 16 + m) ^ ((row & 7) << 3));
    }

#define LOAD_BW(kc)                                                        \
    do {                                                                   \
        _Pragma("unroll")                                                  \
        for (int q = 0; q < 4; ++q)                                        \
            bwc[q] = *(const f16x8*)(whb + q * 32768 + (kc) * 64);         \
    } while (0)

    float cst[2][4] = {{0.f, 0.f, 0.f, 0.f}, {0.f, 0.f, 0.f, 0.f}};
    f16x8 bwc[4];
    __syncthreads();   // idx_lds ready

    // prefetch step-0 gather (8 quads: rt x e, 8B each)
    ushort4 xv[2][4];
#pragma unroll
    for (int rt = 0; rt < 2; ++rt) {
        const int4 i4 = *(const int4*)&idx_lds[rt * 16 + 4 * g];
        xv[rt][0] = *(const ushort4*)(xwr + (unsigned)i4.x + laneoff);
        xv[rt][1] = *(const ushort4*)(xwr + (unsigned)i4.y + laneoff);
        xv[rt][2] = *(const ushort4*)(xwr + (unsigned)i4.z + laneoff);
        xv[rt][3] = *(const ushort4*)(xwr + (unsigned)i4.w + laneoff);
    }
    LOAD_BW(0);   // kc0 for t=1's MFMA phase

    for (int t = 0; t < KST; ++t) {
        const int rb = t & 1;
        const int wb = rb ^ 1;

        // consume prefetched quads into accumulators
        f32x4 acc[2][4];
#pragma unroll
        for (int rt = 0; rt < 2; ++rt)
#pragma unroll
            for (int e = 0; e < 4; ++e) {
                acc[rt][0][e] = h2f(xv[rt][e].x);
                acc[rt][1][e] = h2f(xv[rt][e].y);
                acc[rt][2][e] = h2f(xv[rt][e].z);
                acc[rt][3][e] = h2f(xv[rt][e].w);
            }

        // prefetch next step's gather (rides the barrier)
        if (t + 1 < KST) {
#pragma unroll
            for (int rt = 0; rt < 2; ++rt) {
                const int4 i4 = *(const int4*)&idx_lds[(t + 1) * 32 + rt * 16 + 4 * g];
                xv[rt][0] = *(const ushort4*)(xwr + (unsigned)i4.x + laneoff);
                xv[rt][1] = *(const ushort4*)(xwr + (unsigned)i4.y + laneoff);
                xv[rt][2] = *(const ushort4*)(xwr + (unsigned)i4.z + laneoff);
                xv[rt][3] = *(const ushort4*)(xwr + (unsigned)i4.w + laneoff);
            }
        }

        __builtin_amdgcn_s_setprio(1);
        if (t > 0) {
            const unsigned short* hb = h_lds[rb];
#pragma unroll
            for (int kc = 0; kc < 4; ++kc) {
                f16x8 a[2];
#pragma unroll
                for (int rt = 0; rt < 2; ++rt)
                    a[rt] = *(const f16x8*)&hb[rd_off[kc] + rt * 2048];
#pragma unroll
                for (int rt = 0; rt < 2; ++rt)
#pragma unroll
                    for (int q = 0; q < 4; ++q)
                        acc[rt][q] = mfma16h(a[rt], bwc[q], acc[rt][q]);
                if (kc < 3) LOAD_BW(kc + 1);   // stream next frag set (L2-hot)
            }
        }
        __builtin_amdgcn_s_setprio(0);

        // rcp-fused LSTM cell (pre-scaled algebra): 5 exp2 + 2 rcp / element
        unsigned short* nh = h_lds[wb];
#pragma unroll
        for (int rt = 0; rt < 2; ++rt)
#pragma unroll
            for (int e = 0; e < 4; ++e) {
                const float Ai = __builtin_amdgcn_exp2f(-acc[rt][0][e]);
                const float Af = __builtin_amdgcn_exp2f(-acc[rt][1][e]);
                const float Ag = __builtin_amdgcn_exp2f(-acc[rt][2][e]);
                const float Ao = __builtin_amdgcn_exp2f(-acc[rt][3][e]);
                const float Di = 1.0f + Ai, Df = 1.0f + Af;
                const float Dg = 1.0f + Ag, Do = 1.0f + Ao;
                const float DiDg = Di * Dg;
                const float P  = __builtin_fmaf(-TT, Ag, TT);          // TT*(1-Ag)
                const float num = __builtin_fmaf(cst[rt][e], DiDg, P * Df);
                const float R1 = __builtin_amdgcn_rcpf(Df * DiDg);
                const float csn = num * R1;                            // 2log2e*c'
                cst[rt][e] = csn;
                const float C2 = __builtin_amdgcn_exp2f(-csn);
                const float R2 = __builtin_amdgcn_rcpf(Do * (1.0f + C2));
                nh[wr_off[e] + rt * 2048] = f2h_bits((1.0f - C2) * R2);
            }
        LOAD_BW(0);        // kc0 for next step; latency hides under barrier
        barrier_lgkm();    // h(t) visible; vmcnt stays in flight
    }
#undef LOAD_BW

    // ---- FC + leaky-relu: wave w -> out cols w*16+m, 32 nodes. h in buf[0].
    {
        const unsigned short* hb = h_lds[0];
        const float* fsr = fcs + (size_t)r * HD * HD;
        const float* fnr = fcn + (size_t)r * HD * HD;
        const int col = w * 16 + m;
        f32x4 oacc[2];
        oacc[0] = f4splat(bias[r * HD + col]);
        oacc[1] = oacc[0];
#pragma unroll
        for (int kc = 0; kc < 4; ++kc) {
            const f16x8 bs = load8h(fsr + (size_t)col * HD + kc * 32 + 8 * g);
            const f16x8 bn = load8h(fnr + (size_t)col * HD + kc * 32 + 8 * g);
#pragma unroll
            for (int rt = 0; rt < 2; ++rt) {
                const f16x8 ax = load8h(x + (size_t)(n0 + rt * 16 + m) * HD + kc * 32 + 8 * g);
                const f16x8 ah = *(const f16x8*)&hb[rd_off[kc] + rt * 2048];
                oacc[rt] = mfma16h(ax, bs, oacc[rt]);
                oacc[rt] = mfma16h(ah, bn, oacc[rt]);
            }
        }
#pragma unroll
        for (int rt = 0; rt < 2; ++rt)
#pragma unroll
            for (int e = 0; e < 4; ++e) {
                const int row = rt * 16 + 4 * g + e;
                float v = oacc[rt][e];
                v = v > 0.0f ? v : 0.01f * v;
                Xout[((size_t)(n0 + row) * NRELS + r) * HD + col] = v;
            }
    }
}

// ---------------------------------------------------------------------------
// attention: one wave per node; softmax over 3 relations, f32 throughout
// ---------------------------------------------------------------------------
__global__ __launch_bounds__(256) void attn_kernel(
    const float* __restrict__ X, const float* __restrict__ tc,
    float* __restrict__ out)
{
    const int wv = blockIdx.x * (blockDim.x >> 6) + (threadIdx.x >> 6);
    const int lane = threadIdx.x & 63;
    if (wv >= NN) return;
    const size_t nb = (size_t)wv;

    const float t0 = tc[nb * HD + lane];
    const float t1 = tc[nb * HD + 64 + lane];
    float x0[3], x1[3], sc[3];
#pragma unroll
    for (int r = 0; r < 3; ++r) {
        x0[r] = X[(nb * 3 + r) * HD + lane];
        x1[r] = X[(nb * 3 + r) * HD + 64 + lane];
        float p = x0[r] * t0 + x1[r] * t1;
#pragma unroll
        for (int off = 32; off >= 1; off >>= 1)
            p += __shfl_xor(p, off, 64);
        sc[r] = p;
    }
    const float mx = fmaxf(sc[0], fmaxf(sc[1], sc[2]));
    const float e0 = __expf(sc[0] - mx), e1 = __expf(sc[1] - mx), e2 = __expf(sc[2] - mx);
    const float inv = __builtin_amdgcn_rcpf(e0 + e1 + e2);
    const float a0 = e0 * inv, a1 = e1 * inv, a2 = e2 * inv;
    out[nb * HD + lane]      = a0 * x0[0] + a1 * x0[1] + a2 * x0[2];
    out[nb * HD + 64 + lane] = a0 * x1[0] + a1 * x1[1] + a2 * x1[2];
}

extern "C" void kernel_launch(void* const* d_in, const int* in_sizes, int n_in,
                              void* d_out, int out_size, void* d_ws, size_t ws_size,
                              hipStream_t stream)
{
    const float* x     = (const float*)d_in[0];
    const float* conn  = (const float*)d_in[1];
    const int*   nbr   = (const int*)d_in[2];
    const float* trans = (const float*)d_in[3];
    const float* Wih   = (const float*)d_in[4];
    const float* Whh   = (const float*)d_in[5];
    const float* blstm = (const float*)d_in[6];
    const float* fcs   = (const float*)d_in[7];
    const float* fcn   = (const float*)d_in[8];
    const float* bias  = (const float*)d_in[9];
    float* out = (float*)d_out;

    // ws: xW fp16 [3][N][512] | tc f32 [N][128] | X f32 [N][3][128] | WhhH fp16
    const size_t XW_B = (size_t)NRELS * NN * G4 * 2;     //  50.3 MB
    const size_t TC_B = (size_t)NN * HD * 4;             //   8.4 MB
    const size_t XO_B = (size_t)NN * NRELS * HD * 4;     //  25.2 MB
    const size_t WH_B = (size_t)NRELS * G4 * HD * 2;     //   0.4 MB
    if (ws_size < XW_B + TC_B + XO_B + WH_B) return;     //  84.3 MB floor

    char* wsb = (char*)d_ws;
    unsigned short* xW   = (unsigned short*)wsb;
    float*          tc   = (float*)(wsb + XW_B);
    float*          Xo   = (float*)(wsb + XW_B + TC_B);
    unsigned short* whhh = (unsigned short*)(wsb + XW_B + TC_B + XO_B);

    whh_cvt<<<dim3(NRELS * G4 * HD / 256), 256, 0, stream>>>(Whh, whhh);
    gemm_rt<512, 1><<<dim3(NN / 64, NRELS), 512, 0, stream>>>(x, Wih, blstm, (void*)xW);
    gemm_rt<128, 0><<<dim3(NN / 64, 1), 512, 0, stream>>>(conn, trans, nullptr, (void*)tc);
    lstm_kernel<<<dim3(NN / NPB, NRELS), 512, 0, stream>>>(x, nbr, whhh, fcs, fcn, bias, xW, Xo);
    attn_kernel<<<dim3(NN / 4), 256, 0, stream>>>(Xo, tc, out);
}